// Round 3
// baseline (664.004 us; speedup 1.0000x reference)
//
#include <hip/hip_runtime.h>

typedef unsigned char u8;
typedef unsigned short u16;
typedef unsigned int u32;
typedef unsigned long long u64;
typedef __attribute__((ext_vector_type(8))) short short8;
typedef __attribute__((ext_vector_type(4))) float f32x4;

#define NB 64
#define LL 4096
#define CC 512
#define KK 2048     // kept tokens (extra token at row KK)
#define PPQ 819     // P
#define HH 102      // H
#define KP 2176     // padded all_tokens rows (17*128)
#define PPAD 896    // padded P (7*128)
#define HP 128      // padded H

__device__ __forceinline__ u16 f2bf(float f) {
  u32 u = __float_as_uint(f);
  u += 0x7fffu + ((u >> 16) & 1u);
  return (u16)(u >> 16);
}
__device__ __forceinline__ float bf2f(u16 h) { return __uint_as_float(((u32)h) << 16); }
__device__ __forceinline__ float dec_score(u32 s) {
  u32 u = (s & 0x80000000u) ? (s ^ 0x80000000u) : ~s;
  return __uint_as_float(u);
}
__device__ __forceinline__ u8 f2fp8(float f) {
  return (u8)(__builtin_amdgcn_cvt_pk_fp8_f32(f, 0.f, 0, false) & 0xff);
}

typedef __attribute__((address_space(1))) void gvoid;
typedef __attribute__((address_space(3))) void lvoid;
__device__ __forceinline__ void gload16(const u16* g, u16* l) {
  __builtin_amdgcn_global_load_lds((gvoid*)(g), (lvoid*)(l), 16, 0, 0);
}
__device__ __forceinline__ void gload16b(const u8* g, u8* l) {
  __builtin_amdgcn_global_load_lds((gvoid*)(g), (lvoid*)(l), 16, 0, 0);
}

// ---------- per-batch bitonic sort of composite keys + mask + tail-softmax stats ----------
__global__ __launch_bounds__(1024) void sort_kernel(
    const float* __restrict__ ax, const float* __restrict__ ay,
    u64* __restrict__ keys, float* __restrict__ mask_out, float2* __restrict__ stats)
{
  __shared__ u64 arr[LL];
  __shared__ float red[16];
  int b = blockIdx.x, tid = threadIdx.x;
  for (int i = tid; i < LL; i += 1024) {
    float s = ax[(size_t)b*LL + i] + ay[(size_t)b*LL + i];
    u32 u = __float_as_uint(s);
    u = (u & 0x80000000u) ? ~u : (u | 0x80000000u);
    arr[i] = (((u64)u) << 32) | (u32)(LL - 1 - i);
  }
  __syncthreads();
  for (int k = 2; k <= LL; k <<= 1) {
    for (int j = k >> 1; j > 0; j >>= 1) {
      #pragma unroll
      for (int rep = 0; rep < 4; ++rep) {
        int i = tid + rep * 1024;
        int ixj = i ^ j;
        if (ixj > i) {
          u64 a = arr[i], c = arr[ixj];
          bool desc = ((i & k) == 0);
          if (desc ? (a < c) : (a > c)) { arr[i] = c; arr[ixj] = a; }
        }
      }
      __syncthreads();
    }
  }
  for (int i = tid; i < LL; i += 1024) {
    u64 v = arr[i];
    keys[(size_t)b*LL + i] = v;
    int idx = (LL - 1) - (int)(v & 0xffffffffu);
    mask_out[(size_t)b*LL + idx] = (i < KK) ? 1.0f : 0.0f;
  }
  float m = dec_score((u32)(arr[KK] >> 32));
  float part = 0.f;
  for (int i = KK + tid; i < LL; i += 1024)
    part += expf(dec_score((u32)(arr[i] >> 32)) - m);
  #pragma unroll
  for (int off = 32; off; off >>= 1) part += __shfl_xor(part, off);
  if ((tid & 63) == 0) red[tid >> 6] = part;
  __syncthreads();
  if (tid == 0) {
    float s = 0.f;
    #pragma unroll
    for (int i = 0; i < 16; ++i) s += red[i];
    stats[b] = make_float2(m, s);
  }
}

// ---------- tail weighted partial sums (extra token) ----------
__global__ __launch_bounds__(256) void tail_partial_kernel(
    const float* __restrict__ tokens, const u64* __restrict__ keys,
    const float2* __restrict__ stats, float* __restrict__ partials)
{
  int b = blockIdx.y, rb = blockIdx.x, t = threadIdx.x;
  float m = stats[b].x, inv = 1.0f / stats[b].y;
  const u64* kb = keys + (size_t)b*LL + KK + rb*256;
  float a0 = 0.f, a1 = 0.f;
  #pragma unroll 4
  for (int r = 0; r < 256; ++r) {
    u64 kk = kb[r];
    int idx = (LL - 1) - (int)(kk & 0xffffffffu);
    float w = expf(dec_score((u32)(kk >> 32)) - m) * inv;
    const float* src = tokens + ((size_t)b*LL + idx)*CC;
    a0 += w * src[t];
    a1 += w * src[t + 256];
  }
  float* dst = partials + (size_t)(b*8 + rb)*CC;
  dst[t] = a0; dst[t + 256] = a1;
}

// ---------- gather all_tokens (bf16) + per-row LN stats ----------
__global__ __launch_bounds__(256) void gather_ln_kernel(
    const float* __restrict__ tokens, const u64* __restrict__ keys,
    const float* __restrict__ partials,
    u16* __restrict__ allT, float2* __restrict__ rowstats)
{
  int b = blockIdx.y;
  int r = blockIdx.x*4 + (threadIdx.x >> 6);
  int lane = threadIdx.x & 63;
  size_t orow = ((size_t)b*KP + r)*CC;
  int c0 = lane*8;
  if (r > KK) {
    short8 z = {};
    *(short8*)(allT + orow + c0) = z;
    if (lane == 0) rowstats[(size_t)b*KP + r] = make_float2(0.f, 0.f);
    return;
  }
  float x[8];
  if (r < KK) {
    u64 kk = keys[(size_t)b*LL + r];
    int idx = (LL - 1) - (int)(kk & 0xffffffffu);
    const float* src = tokens + ((size_t)b*LL + idx)*CC + c0;
    f32x4 v0 = *(const f32x4*)src;
    f32x4 v1 = *(const f32x4*)(src + 4);
    #pragma unroll
    for (int j = 0; j < 4; ++j) { x[j] = v0[j]; x[j+4] = v1[j]; }
  } else {
    #pragma unroll
    for (int j = 0; j < 8; ++j) {
      float s = 0.f;
      #pragma unroll
      for (int p = 0; p < 8; ++p) s += partials[(size_t)(b*8 + p)*CC + c0 + j];
      x[j] = s;
    }
  }
  float s = 0.f;
  #pragma unroll
  for (int j = 0; j < 8; ++j) s += x[j];
  #pragma unroll
  for (int off = 32; off; off >>= 1) s += __shfl_xor(s, off);
  float mu = s * (1.0f/CC);
  float vs = 0.f;
  #pragma unroll
  for (int j = 0; j < 8; ++j) { float d = x[j] - mu; vs += d*d; }
  #pragma unroll
  for (int off = 32; off; off >>= 1) vs += __shfl_xor(vs, off);
  float rstd = rsqrtf(vs * (1.0f/CC) + 1e-5f);
  short8 raw;
  #pragma unroll
  for (int j = 0; j < 8; ++j) raw[j] = (short)f2bf(x[j]);
  *(short8*)(allT + orow + c0) = raw;
  if (lane == 0) rowstats[(size_t)b*KP + r] = make_float2(mu, rstd);
}

// ---------- weights -> padded transposed bf16, zero sums ----------
__global__ __launch_bounds__(256) void prep_kernel(
    const float* __restrict__ w1, const float* __restrict__ w2,
    u16* __restrict__ w1T, u16* __restrict__ w2T, float* __restrict__ sums)
{
  int id = blockIdx.x*256 + threadIdx.x;
  if (id < HP*CC) {                       // w1T[h][c] = w1[c][h]
    int r = id >> 9, c = id & 511;
    w1T[id] = (r < HH) ? f2bf(w1[c*HH + r]) : (u16)0;
  } else if (id < HP*CC + PPAD*HP) {      // w2T[p][h] = w2[h][p]
    int id2 = id - HP*CC;
    int r = id2 >> 7, c = id2 & 127;
    w2T[id2] = (r < PPQ && c < HH) ? f2bf(w2[(size_t)c*PPQ + r]) : (u16)0;
  } else {
    int id3 = id - HP*CC - PPAD*HP;
    if (id3 < NB*PPAD) sums[id3] = 0.f;
  }
}

// ---------- allT [k][c] -> allTT [c][k] per batch, fp8 output ----------
__global__ __launch_bounds__(256) void transpose_kernel(
    const u16* __restrict__ allT, u8* __restrict__ allTT)
{
  __shared__ u16 t[64][72];
  int b = blockIdx.z;
  int r0 = blockIdx.x*64, c0 = blockIdx.y*64;
  const u16* src = allT + ((size_t)b*KP + r0)*CC + c0;
  int tr = threadIdx.x >> 3, tc = (threadIdx.x & 7)*8;
  #pragma unroll
  for (int i = 0; i < 2; ++i)
    *(short8*)(&t[tr + i*32][tc]) = *(const short8*)(src + (size_t)(tr + i*32)*CC + tc);
  __syncthreads();
  u8* dst = allTT + ((size_t)b*CC + c0)*KP + r0;
  #pragma unroll
  for (int i = 0; i < 2; ++i) {
    int rr = tr + i*32;
    float f[8];
    #pragma unroll
    for (int j = 0; j < 8; ++j) f[j] = bf2f(t[tc + j][rr]);
    u32 lo = __builtin_amdgcn_cvt_pk_fp8_f32(f[0], f[1], 0, false);
    lo = __builtin_amdgcn_cvt_pk_fp8_f32(f[2], f[3], lo, true);
    u32 hi = __builtin_amdgcn_cvt_pk_fp8_f32(f[4], f[5], 0, false);
    hi = __builtin_amdgcn_cvt_pk_fp8_f32(f[6], f[7], hi, true);
    uint2 v = make_uint2(lo, hi);
    *(uint2*)(dst + (size_t)rr*KP + tc) = v;
  }
}

// ---------- bf16 128x128x32 GEMM, A[M][K] x BT[N][K] ----------
// MODE 0: A=allT (LN fused, reg-staged), B=w1T -> hbuf bf16 gelu, cols>=HH zero
// MODE 1: A=w2T (M=p), B=hbuf[b] (N=k) -> wgtE[b][p][k] = fp8(exp((v+b2[p])*scale)),
//         per-row exp sums (k<=KK) via shuffle + atomic
template<int MODE>
__global__ __launch_bounds__(256) void gemm_kernel(
    const u16* __restrict__ A, const u16* __restrict__ Bm, void* __restrict__ Cv,
    const float* __restrict__ bias, const float* __restrict__ scalep,
    const float2* __restrict__ rowstats, const float* __restrict__ gvec,
    const float* __restrict__ bvec, float* __restrict__ sums)
{
  __shared__ u16 As[128*32];
  __shared__ u16 Bs[128*32];

  constexpr int KSTEPS = (MODE==0) ? 16 : 4;
  constexpr int LDA    = (MODE==0) ? CC : HP;
  constexpr int LDB    = (MODE==0) ? CC : HP;

  int chunk = gridDim.x >> 3;
  int lg = (blockIdx.x & 7)*chunk + (blockIdx.x >> 3);
  int b, m0, n0;
  if (MODE == 0) { b = 0;      m0 = lg*128;          n0 = 0; }
  else           { b = lg/119; int t2 = lg%119; m0 = (t2%7)*128; n0 = (t2/7)*128; }

  const u16* Ab = A; const u16* Bb = Bm;
  if (MODE == 1) { Bb = Bm + (size_t)b*KP*HP; }

  int tid = threadIdx.x, lane = tid & 63, wave = tid >> 6;
  int sr = tid >> 2, sc = (tid & 3)*8;
  int wr = (wave >> 1)*64, wc = (wave & 1)*64;

  float2 st0 = make_float2(0.f,0.f), st1 = st0;
  if (MODE == 0) { st0 = rowstats[m0 + sr]; st1 = rowstats[m0 + 64 + sr]; }

  f32x4 acc[4][4];
  #pragma unroll
  for (int m = 0; m < 4; ++m)
    #pragma unroll
    for (int n = 0; n < 4; ++n) acc[m][n] = (f32x4){0.f,0.f,0.f,0.f};

  for (int ks = 0; ks < KSTEPS; ++ks) {
    int k0 = ks*32;
    if (MODE == 0) {
      const u16* s0 = Ab + (size_t)(m0 + sr)*LDA + k0 + sc;
      short8 v = *(const short8*)s0;
      short8 w = *(const short8*)(s0 + (size_t)64*LDA);
      short8 o1, o2;
      #pragma unroll
      for (int j = 0; j < 8; ++j) {
        int kc = k0 + sc + j;
        float g = gvec[kc], bb = bvec[kc];
        o1[j] = (short)f2bf((bf2f((u16)v[j]) - st0.x)*st0.y*g + bb);
        o2[j] = (short)f2bf((bf2f((u16)w[j]) - st1.x)*st1.y*g + bb);
      }
      *(short8*)(As + tid*8) = o1;
      *(short8*)(As + 2048 + tid*8) = o2;
    } else {
      gload16(Ab + (size_t)(m0 + sr)*LDA + k0 + sc,      As + wave*512);
      gload16(Ab + (size_t)(m0 + 64 + sr)*LDA + k0 + sc, As + 2048 + wave*512);
    }
    gload16(Bb + (size_t)(n0 + sr)*LDB + k0 + sc,      Bs + wave*512);
    gload16(Bb + (size_t)(n0 + 64 + sr)*LDB + k0 + sc, Bs + 2048 + wave*512);
    __syncthreads();
    const u16* ap = As + (wr + (lane & 15))*32 + (lane >> 4)*8;
    const u16* bp = Bs + (wc + (lane & 15))*32 + (lane >> 4)*8;
    short8 af[4], bfr[4];
    #pragma unroll
    for (int m = 0; m < 4; ++m) af[m] = *(const short8*)(ap + m*16*32);
    #pragma unroll
    for (int n = 0; n < 4; ++n) bfr[n] = *(const short8*)(bp + n*16*32);
    #pragma unroll
    for (int n = 0; n < 4; ++n)
      #pragma unroll
      for (int m = 0; m < 4; ++m)
        acc[m][n] = __builtin_amdgcn_mfma_f32_16x16x32_bf16(af[m], bfr[n], acc[m][n], 0, 0, 0);
    __syncthreads();
  }

  if (MODE == 0) {
    #pragma unroll
    for (int m = 0; m < 4; ++m)
      #pragma unroll
      for (int n = 0; n < 4; ++n)
        #pragma unroll
        for (int q = 0; q < 4; ++q) {
          int gm = m0 + wr + m*16 + (lane >> 4)*4 + q;
          int gn = n0 + wc + n*16 + (lane & 15);
          float r = 0.f;
          if (gn < HH) {
            float xx = acc[m][n][q] + bias[gn];
            r = 0.5f*xx*(1.0f + erff(xx*0.70710678118654752f));
          }
          ((u16*)Cv)[(size_t)gm*HP + gn] = f2bf(r);
        }
  } else {
    float sc_ = scalep[0];
    #pragma unroll
    for (int m = 0; m < 4; ++m) {
      #pragma unroll
      for (int q = 0; q < 4; ++q) {
        int gm = m0 + wr + m*16 + (lane >> 4)*4 + q;   // p row
        float bb = bias[gm];
        float s_local = 0.f;
        #pragma unroll
        for (int n = 0; n < 4; ++n) {
          int gn = n0 + wc + n*16 + (lane & 15);        // k col
          float v2 = (acc[m][n][q] + bb)*sc_;
          float e = __expf(fminf(v2, 5.5f));
          ((u8*)Cv)[(size_t)b*PPAD*KP + (size_t)gm*KP + gn] = f2fp8(e);
          if (gn <= KK) s_local += e;
        }
        s_local += __shfl_xor(s_local, 1);
        s_local += __shfl_xor(s_local, 2);
        s_local += __shfl_xor(s_local, 4);
        s_local += __shfl_xor(s_local, 8);
        if ((lane & 15) == 0) atomicAdd(&sums[b*PPAD + gm], s_local);
      }
    }
  }
}

// ---------- fp8 128x128x64 GEMM: out[b][p][c] = (wgtE[p][:] . allTT[c][:]) / sums[b][p] ----------
__global__ __launch_bounds__(256) void gemm2_kernel(
    const u8* __restrict__ wgtE, const u8* __restrict__ allTT,
    float* __restrict__ out, const float* __restrict__ sums)
{
  __shared__ u8 As[128*64];
  __shared__ u8 Bs[128*64];

  int chunk = gridDim.x >> 3;
  int lg = (blockIdx.x & 7)*chunk + (blockIdx.x >> 3);
  int b = lg/28; int t2 = lg%28;
  int n0 = (t2/7)*128, m0 = (t2%7)*128;

  const u8* Ab = wgtE + (size_t)b*PPAD*KP;
  const u8* Bb = allTT + (size_t)b*CC*KP;

  int tid = threadIdx.x, lane = tid & 63, wave = tid >> 6;
  int sr = tid >> 2, scB = (tid & 3)*16;
  int wr = (wave >> 1)*64, wc = (wave & 1)*64;

  f32x4 acc[4][4];
  #pragma unroll
  for (int m = 0; m < 4; ++m)
    #pragma unroll
    for (int n = 0; n < 4; ++n) acc[m][n] = (f32x4){0.f,0.f,0.f,0.f};

  for (int ks = 0; ks < 34; ++ks) {
    int k0 = ks*64;
    gload16b(Ab + (size_t)(m0 + sr)*KP + k0 + scB,      As + wave*1024);
    gload16b(Ab + (size_t)(m0 + 64 + sr)*KP + k0 + scB, As + 4096 + wave*1024);
    gload16b(Bb + (size_t)(n0 + sr)*KP + k0 + scB,      Bs + wave*1024);
    gload16b(Bb + (size_t)(n0 + 64 + sr)*KP + k0 + scB, Bs + 4096 + wave*1024);
    __syncthreads();
    #pragma unroll
    for (int sub = 0; sub < 2; ++sub) {
      const u8* ap = As + (wr + (lane & 15))*64 + sub*32 + (lane >> 4)*8;
      const u8* bp = Bs + (wc + (lane & 15))*64 + sub*32 + (lane >> 4)*8;
      long af[4], bfr[4];
      #pragma unroll
      for (int m = 0; m < 4; ++m) af[m] = *(const long*)(ap + m*16*64);
      #pragma unroll
      for (int n = 0; n < 4; ++n) bfr[n] = *(const long*)(bp + n*16*64);
      #pragma unroll
      for (int n = 0; n < 4; ++n)
        #pragma unroll
        for (int m = 0; m < 4; ++m)
          acc[m][n] = __builtin_amdgcn_mfma_f32_16x16x32_fp8_fp8(af[m], bfr[n], acc[m][n], 0, 0, 0);
    }
    __syncthreads();
  }

  #pragma unroll
  for (int m = 0; m < 4; ++m)
    #pragma unroll
    for (int q = 0; q < 4; ++q) {
      int gm = m0 + wr + m*16 + (lane >> 4)*4 + q;
      if (gm < PPQ) {
        float inv = 1.0f / sums[b*PPAD + gm];
        #pragma unroll
        for (int n = 0; n < 4; ++n) {
          int gn = n0 + wc + n*16 + (lane & 15);
          out[(size_t)b*PPQ*CC + (size_t)gm*CC + gn] = acc[m][n][q]*inv;
        }
      }
    }
}

extern "C" void kernel_launch(void* const* d_in, const int* in_sizes, int n_in,
                              void* d_out, int out_size, void* d_ws, size_t ws_size,
                              hipStream_t stream)
{
  const float* tokens = (const float*)d_in[0];
  const float* ax  = (const float*)d_in[1];
  const float* ay  = (const float*)d_in[2];
  const float* ln_g = (const float*)d_in[3];
  const float* ln_b = (const float*)d_in[4];
  const float* w1  = (const float*)d_in[5];
  const float* b1  = (const float*)d_in[6];
  const float* w2  = (const float*)d_in[7];
  const float* b2  = (const float*)d_in[8];
  const float* scale = (const float*)d_in[9];
  float* out_super = (float*)d_out;
  float* out_mask  = out_super + (size_t)NB*PPQ*CC;

  char* ws = (char*)d_ws;
  size_t off = 0;
  u64* keys = (u64*)(ws + off);          off += (size_t)NB*LL*8;
  float2* stats = (float2*)(ws + off);   off += 512;
  float* partials = (float*)(ws + off);  off += (size_t)NB*8*CC*4;
  float2* rowstats = (float2*)(ws + off);off += (size_t)NB*KP*8;
  u16* allT = (u16*)(ws + off);          off += (size_t)NB*KP*CC*2;
  size_t regA_end = off;
  u8* wgtE = (u8*)ws;                    // aliases region A (dead before GEMM1)
  size_t wgtE_end = (size_t)NB*PPAD*KP;  // fp8: 124.8 MB
  off = (regA_end > wgtE_end) ? regA_end : wgtE_end;
  u8*  allTT = (u8*)(ws + off);  off += (size_t)NB*CC*KP;
  u16* hbuf  = (u16*)(ws + off); off += (size_t)NB*KP*HP*2;
  u16* w1T   = (u16*)(ws + off); off += (size_t)HP*CC*2;
  u16* w2T   = (u16*)(ws + off); off += (size_t)PPAD*HP*2;
  float* sums = (float*)(ws + off); off += (size_t)NB*PPAD*4;
  if (off > ws_size) return;

  prep_kernel<<<928, 256, 0, stream>>>(w1, w2, w1T, w2T, sums);
  sort_kernel<<<NB, 1024, 0, stream>>>(ax, ay, keys, out_mask, stats);
  tail_partial_kernel<<<dim3(8, NB), 256, 0, stream>>>(tokens, keys, stats, partials);
  gather_ln_kernel<<<dim3(KP/4, NB), 256, 0, stream>>>(tokens, keys, partials, allT, rowstats);
  transpose_kernel<<<dim3(KP/64, CC/64, NB), 256, 0, stream>>>(allT, allTT);
  gemm_kernel<0><<<(NB*KP)/128, 256, 0, stream>>>(
      allT, w1T, hbuf, b1, scale, rowstats, ln_g, ln_b, nullptr);
  gemm_kernel<1><<<(PPAD/128)*(KP/128)*NB, 256, 0, stream>>>(
      w2T, hbuf, wgtE, b2, scale, nullptr, nullptr, nullptr, sums);
  gemm2_kernel<<<(PPAD/128)*(CC/128)*NB, 256, 0, stream>>>(
      wgtE, allTT, out_super, sums);
}

// Round 4
// 640.728 us; speedup vs baseline: 1.0363x; 1.0363x over previous
//
#include <hip/hip_runtime.h>

typedef unsigned char u8;
typedef unsigned short u16;
typedef unsigned int u32;
typedef unsigned long long u64;
typedef __attribute__((ext_vector_type(8))) short short8;
typedef __attribute__((ext_vector_type(4))) float f32x4;

#define NB 64
#define LL 4096
#define CC 512
#define KK 2048     // kept tokens (extra token at row KK)
#define PPQ 819     // P
#define HH 102      // H
#define KP 2176     // padded all_tokens rows (34*64)
#define PPAD 896    // padded P (7*128)
#define HP 128      // padded H
#define NCH 34      // K chunks of 64

__device__ __forceinline__ u16 f2bf(float f) {
  u32 u = __float_as_uint(f);
  u += 0x7fffu + ((u >> 16) & 1u);
  return (u16)(u >> 16);
}
__device__ __forceinline__ float bf2f(u16 h) { return __uint_as_float(((u32)h) << 16); }
__device__ __forceinline__ float dec_score(u32 s) {
  u32 u = (s & 0x80000000u) ? (s ^ 0x80000000u) : ~s;
  return __uint_as_float(u);
}

typedef __attribute__((address_space(1))) void gvoid;
typedef __attribute__((address_space(3))) void lvoid;
__device__ __forceinline__ void gload16(const u16* g, u16* l) {
  __builtin_amdgcn_global_load_lds((gvoid*)(g), (lvoid*)(l), 16, 0, 0);
}

// ---------- per-batch bitonic sort of composite keys + mask + tail-softmax stats ----------
__global__ __launch_bounds__(1024) void sort_kernel(
    const float* __restrict__ ax, const float* __restrict__ ay,
    u64* __restrict__ keys, float* __restrict__ mask_out, float2* __restrict__ stats)
{
  __shared__ u64 arr[LL];
  __shared__ float red[16];
  int b = blockIdx.x, tid = threadIdx.x;
  for (int i = tid; i < LL; i += 1024) {
    float s = ax[(size_t)b*LL + i] + ay[(size_t)b*LL + i];
    u32 u = __float_as_uint(s);
    u = (u & 0x80000000u) ? ~u : (u | 0x80000000u);
    arr[i] = (((u64)u) << 32) | (u32)(LL - 1 - i);
  }
  __syncthreads();
  for (int k = 2; k <= LL; k <<= 1) {
    for (int j = k >> 1; j > 0; j >>= 1) {
      #pragma unroll
      for (int rep = 0; rep < 4; ++rep) {
        int i = tid + rep * 1024;
        int ixj = i ^ j;
        if (ixj > i) {
          u64 a = arr[i], c = arr[ixj];
          bool desc = ((i & k) == 0);
          if (desc ? (a < c) : (a > c)) { arr[i] = c; arr[ixj] = a; }
        }
      }
      __syncthreads();
    }
  }
  for (int i = tid; i < LL; i += 1024) {
    u64 v = arr[i];
    keys[(size_t)b*LL + i] = v;
    int idx = (LL - 1) - (int)(v & 0xffffffffu);
    mask_out[(size_t)b*LL + idx] = (i < KK) ? 1.0f : 0.0f;
  }
  float m = dec_score((u32)(arr[KK] >> 32));
  float part = 0.f;
  for (int i = KK + tid; i < LL; i += 1024)
    part += expf(dec_score((u32)(arr[i] >> 32)) - m);
  #pragma unroll
  for (int off = 32; off; off >>= 1) part += __shfl_xor(part, off);
  if ((tid & 63) == 0) red[tid >> 6] = part;
  __syncthreads();
  if (tid == 0) {
    float s = 0.f;
    #pragma unroll
    for (int i = 0; i < 16; ++i) s += red[i];
    stats[b] = make_float2(m, s);
  }
}

// ---------- tail weighted partial sums (extra token) ----------
__global__ __launch_bounds__(256) void tail_partial_kernel(
    const float* __restrict__ tokens, const u64* __restrict__ keys,
    const float2* __restrict__ stats, float* __restrict__ partials)
{
  int b = blockIdx.y, rb = blockIdx.x, t = threadIdx.x;
  float m = stats[b].x, inv = 1.0f / stats[b].y;
  const u64* kb = keys + (size_t)b*LL + KK + rb*256;
  float a0 = 0.f, a1 = 0.f;
  #pragma unroll 4
  for (int r = 0; r < 256; ++r) {
    u64 kk = kb[r];
    int idx = (LL - 1) - (int)(kk & 0xffffffffu);
    float w = expf(dec_score((u32)(kk >> 32)) - m) * inv;
    const float* src = tokens + ((size_t)b*LL + idx)*CC;
    a0 += w * src[t];
    a1 += w * src[t + 256];
  }
  float* dst = partials + (size_t)(b*8 + rb)*CC;
  dst[t] = a0; dst[t + 256] = a1;
}

// ---------- gather all_tokens (bf16) + per-row LN stats ----------
__global__ __launch_bounds__(256) void gather_ln_kernel(
    const float* __restrict__ tokens, const u64* __restrict__ keys,
    const float* __restrict__ partials,
    u16* __restrict__ allT, float2* __restrict__ rowstats)
{
  int b = blockIdx.y;
  int r = blockIdx.x*4 + (threadIdx.x >> 6);
  int lane = threadIdx.x & 63;
  size_t orow = ((size_t)b*KP + r)*CC;
  int c0 = lane*8;
  if (r > KK) {
    short8 z = {};
    *(short8*)(allT + orow + c0) = z;
    if (lane == 0) rowstats[(size_t)b*KP + r] = make_float2(0.f, 0.f);
    return;
  }
  float x[8];
  if (r < KK) {
    u64 kk = keys[(size_t)b*LL + r];
    int idx = (LL - 1) - (int)(kk & 0xffffffffu);
    const float* src = tokens + ((size_t)b*LL + idx)*CC + c0;
    f32x4 v0 = *(const f32x4*)src;
    f32x4 v1 = *(const f32x4*)(src + 4);
    #pragma unroll
    for (int j = 0; j < 4; ++j) { x[j] = v0[j]; x[j+4] = v1[j]; }
  } else {
    #pragma unroll
    for (int j = 0; j < 8; ++j) {
      float s = 0.f;
      #pragma unroll
      for (int p = 0; p < 8; ++p) s += partials[(size_t)(b*8 + p)*CC + c0 + j];
      x[j] = s;
    }
  }
  float s = 0.f;
  #pragma unroll
  for (int j = 0; j < 8; ++j) s += x[j];
  #pragma unroll
  for (int off = 32; off; off >>= 1) s += __shfl_xor(s, off);
  float mu = s * (1.0f/CC);
  float vs = 0.f;
  #pragma unroll
  for (int j = 0; j < 8; ++j) { float d = x[j] - mu; vs += d*d; }
  #pragma unroll
  for (int off = 32; off; off >>= 1) vs += __shfl_xor(vs, off);
  float rstd = rsqrtf(vs * (1.0f/CC) + 1e-5f);
  short8 raw;
  #pragma unroll
  for (int j = 0; j < 8; ++j) raw[j] = (short)f2bf(x[j]);
  *(short8*)(allT + orow + c0) = raw;
  if (lane == 0) rowstats[(size_t)b*KP + r] = make_float2(mu, rstd);
}

// ---------- weights -> padded transposed bf16 ----------
__global__ __launch_bounds__(256) void prep_kernel(
    const float* __restrict__ w1, const float* __restrict__ w2,
    u16* __restrict__ w1T, u16* __restrict__ w2T)
{
  int id = blockIdx.x*256 + threadIdx.x;
  if (id < HP*CC) {                       // w1T[h][c] = w1[c][h]
    int r = id >> 9, c = id & 511;
    w1T[id] = (r < HH) ? f2bf(w1[c*HH + r]) : (u16)0;
  } else {                                // w2T[p][h] = w2[h][p]
    int id2 = id - HP*CC;
    if (id2 < PPAD*HP) {
      int r = id2 >> 7, c = id2 & 127;
      w2T[id2] = (r < PPQ && c < HH) ? f2bf(w2[(size_t)c*PPQ + r]) : (u16)0;
    }
  }
}

// ---------- allT [k][c] -> allTT [c][k] per batch, fp8 output ----------
__global__ __launch_bounds__(256) void transpose_kernel(
    const u16* __restrict__ allT, u8* __restrict__ allTT)
{
  __shared__ u16 t[64][72];
  int b = blockIdx.z;
  int r0 = blockIdx.x*64, c0 = blockIdx.y*64;
  const u16* src = allT + ((size_t)b*KP + r0)*CC + c0;
  int tr = threadIdx.x >> 3, tc = (threadIdx.x & 7)*8;
  #pragma unroll
  for (int i = 0; i < 2; ++i)
    *(short8*)(&t[tr + i*32][tc]) = *(const short8*)(src + (size_t)(tr + i*32)*CC + tc);
  __syncthreads();
  u8* dst = allTT + ((size_t)b*CC + c0)*KP + r0;
  #pragma unroll
  for (int i = 0; i < 2; ++i) {
    int rr = tr + i*32;
    float f[8];
    #pragma unroll
    for (int j = 0; j < 8; ++j) f[j] = bf2f(t[tc + j][rr]);
    u32 lo = __builtin_amdgcn_cvt_pk_fp8_f32(f[0], f[1], 0, false);
    lo = __builtin_amdgcn_cvt_pk_fp8_f32(f[2], f[3], lo, true);
    u32 hi = __builtin_amdgcn_cvt_pk_fp8_f32(f[4], f[5], 0, false);
    hi = __builtin_amdgcn_cvt_pk_fp8_f32(f[6], f[7], hi, true);
    uint2 v = make_uint2(lo, hi);
    *(uint2*)(dst + (size_t)rr*KP + tc) = v;
  }
}

// ---------- GEMM0: bf16 128x128x32, A=allT (LN fused reg-staged), B=w1T -> hbuf gelu ----------
__global__ __launch_bounds__(256) void gemm0_kernel(
    const u16* __restrict__ A, const u16* __restrict__ Bm, u16* __restrict__ Cv,
    const float* __restrict__ bias, const float2* __restrict__ rowstats,
    const float* __restrict__ gvec, const float* __restrict__ bvec)
{
  __shared__ u16 As[128*32];
  __shared__ u16 Bs[128*32];

  int chunk = gridDim.x >> 3;
  int lg = (blockIdx.x & 7)*chunk + (blockIdx.x >> 3);
  int m0 = lg*128;

  int tid = threadIdx.x, lane = tid & 63, wave = tid >> 6;
  int sr = tid >> 2, sc = (tid & 3)*8;
  int wr = (wave >> 1)*64, wc = (wave & 1)*64;

  float2 st0 = rowstats[m0 + sr], st1 = rowstats[m0 + 64 + sr];

  f32x4 acc[4][4];
  #pragma unroll
  for (int m = 0; m < 4; ++m)
    #pragma unroll
    for (int n = 0; n < 4; ++n) acc[m][n] = (f32x4){0.f,0.f,0.f,0.f};

  for (int ks = 0; ks < 16; ++ks) {
    int k0 = ks*32;
    {
      const u16* s0 = A + (size_t)(m0 + sr)*CC + k0 + sc;
      short8 v = *(const short8*)s0;
      short8 w = *(const short8*)(s0 + (size_t)64*CC);
      short8 o1, o2;
      #pragma unroll
      for (int j = 0; j < 8; ++j) {
        int kc = k0 + sc + j;
        float g = gvec[kc], bb = bvec[kc];
        o1[j] = (short)f2bf((bf2f((u16)v[j]) - st0.x)*st0.y*g + bb);
        o2[j] = (short)f2bf((bf2f((u16)w[j]) - st1.x)*st1.y*g + bb);
      }
      *(short8*)(As + tid*8) = o1;
      *(short8*)(As + 2048 + tid*8) = o2;
    }
    gload16(Bm + (size_t)sr*CC + k0 + sc,        Bs + wave*512);
    gload16(Bm + (size_t)(64 + sr)*CC + k0 + sc, Bs + 2048 + wave*512);
    __syncthreads();
    const u16* ap = As + (wr + (lane & 15))*32 + (lane >> 4)*8;
    const u16* bp = Bs + (wc + (lane & 15))*32 + (lane >> 4)*8;
    short8 af[4], bfr[4];
    #pragma unroll
    for (int m = 0; m < 4; ++m) af[m] = *(const short8*)(ap + m*16*32);
    #pragma unroll
    for (int n = 0; n < 4; ++n) bfr[n] = *(const short8*)(bp + n*16*32);
    #pragma unroll
    for (int n = 0; n < 4; ++n)
      #pragma unroll
      for (int m = 0; m < 4; ++m)
        acc[m][n] = __builtin_amdgcn_mfma_f32_16x16x32_bf16(af[m], bfr[n], acc[m][n], 0, 0, 0);
    __syncthreads();
  }

  #pragma unroll
  for (int m = 0; m < 4; ++m)
    #pragma unroll
    for (int n = 0; n < 4; ++n)
      #pragma unroll
      for (int q = 0; q < 4; ++q) {
        int gm = m0 + wr + m*16 + (lane >> 4)*4 + q;
        int gn = wc + n*16 + (lane & 15);
        float r = 0.f;
        if (gn < HH) {
          float xx = acc[m][n][q] + bias[gn];
          r = 0.5f*xx*(1.0f + erff(xx*0.70710678118654752f));
        }
        Cv[(size_t)gm*HP + gn] = f2bf(r);
      }
}

// ---------- fused: logits (bf16 MFMA) + exp + PV (fp8 MFMA) + normalize ----------
// block: (batch b, p-tile of 128). 8 waves.
// logits wave grid: kgrp = wave&3 (16 k-rows), pgrpL = wave>>2 (64 p)
// PV wave grid:     pgrpV = wave&1 (64 p),     cgrp = wave>>1 (128 c)
__global__ __launch_bounds__(512, 2) void fused_kernel(
    const u16* __restrict__ hbuf,   // [b][KP][HP] bf16
    const u16* __restrict__ w2T,    // [PPAD][HP] bf16
    const u8*  __restrict__ allTT,  // [b][CC][KP] fp8
    const float* __restrict__ b2, const float* __restrict__ scalep,
    float* __restrict__ out)
{
  __shared__ u16 w2s[128*128];   // 32 KB, row=p (256B), units XOR (p&7)
  __shared__ u16 hs[64*128];     // 16 KB, row=k (256B), units XOR (k&7)
  __shared__ u8  ps[128*64];     // 8 KB,  row=p (64B),  8B-units XOR (p&7)<<3
  __shared__ float sums[128];

  int g = blockIdx.x;
  int t7 = g >> 3;
  int b = (g & 7)*8 + t7/7;
  int pt = t7 - (t7/7)*7;
  int p0 = pt*128;

  int tid = threadIdx.x, lane = tid & 63, wave = tid >> 6;
  int kgrp = wave & 3, pgrpL = wave >> 2;
  int pgrpV = wave & 1, cgrp = wave >> 1;

  const u16* hbg = hbuf + (size_t)b*KP*HP;
  const u8*  abt = allTT + (size_t)b*CC*KP;

  // stage w2 tile (swizzled write), zero sums
  #pragma unroll
  for (int i = 0; i < 4; ++i) {
    int f = i*512 + tid;            // 2048 units of 16B
    int p = f >> 4, u = f & 15;
    short8 v = *(const short8*)(w2T + (size_t)(p0 + p)*HP + u*8);
    *(short8*)(w2s + p*128 + ((u ^ (p & 7))*8)) = v;
  }
  if (tid < 128) sums[tid] = 0.f;

  // stage hbuf chunk 0 (pre-swizzled source, linear LDS dest)
  #pragma unroll
  for (int r = 0; r < 2; ++r) {
    int f = r*512 + tid;            // 1024 units
    int k = f >> 4, u = f & 15;
    gload16(hbg + (size_t)k*HP + ((u ^ (k & 7))*8), hs + r*4096 + wave*512);
  }

  float sc_ = scalep[0];
  float b2v[4];
  #pragma unroll
  for (int f = 0; f < 4; ++f) {
    int gp = p0 + pgrpL*64 + f*16 + (lane & 15);
    b2v[f] = (gp < PPQ) ? b2[gp] : 0.f;
  }

  float s_acc[4] = {0.f, 0.f, 0.f, 0.f};
  f32x4 acc[4][8];
  #pragma unroll
  for (int mf = 0; mf < 4; ++mf)
    #pragma unroll
    for (int nf = 0; nf < 8; ++nf) acc[mf][nf] = (f32x4){0.f,0.f,0.f,0.f};

  for (int kc = 0; kc < NCH; ++kc) {
    __syncthreads();   // hbuf chunk kc staged; P_lds of kc-1 consumed

    // issue PV B-fragment loads early (L2-resident allTT) — consumed after next barrier
    long breg[8][2];
    #pragma unroll
    for (int nf = 0; nf < 8; ++nf)
      #pragma unroll
      for (int sl = 0; sl < 2; ++sl) {
        int c = cgrp*128 + nf*16 + (lane & 15);
        breg[nf][sl] = *(const long*)(abt + (size_t)c*KP + kc*64 + sl*32 + (lane >> 4)*8);
      }

    // logits: L^T[k][p] tile strip per wave
    short8 af[4];
    {
      int kr = kgrp*16 + (lane & 15);
      #pragma unroll
      for (int s4 = 0; s4 < 4; ++s4) {
        int u = s4*4 + (lane >> 4);
        af[s4] = *(const short8*)(hs + kr*128 + ((u ^ (kr & 7))*8));
      }
    }
    f32x4 Lacc[4];
    #pragma unroll
    for (int f = 0; f < 4; ++f) Lacc[f] = (f32x4){0.f,0.f,0.f,0.f};
    #pragma unroll
    for (int f = 0; f < 4; ++f) {
      int pr = pgrpL*64 + f*16 + (lane & 15);
      #pragma unroll
      for (int s4 = 0; s4 < 4; ++s4) {
        int u = s4*4 + (lane >> 4);
        short8 bf = *(const short8*)(w2s + pr*128 + ((u ^ (pr & 7))*8));
        Lacc[f] = __builtin_amdgcn_mfma_f32_16x16x32_bf16(af[s4], bf, Lacc[f], 0, 0, 0);
      }
    }

    // exp + mask-sum + fp8 pack -> P_lds
    #pragma unroll
    for (int f = 0; f < 4; ++f) {
      float e[4];
      #pragma unroll
      for (int q = 0; q < 4; ++q) {
        float v = (Lacc[f][q] + b2v[f])*sc_;
        e[q] = __expf(fminf(v, 5.5f));
        int kg = kc*64 + kgrp*16 + (lane >> 4)*4 + q;
        if (kg <= KK) s_acc[f] += e[q];
      }
      u32 w = __builtin_amdgcn_cvt_pk_fp8_f32(e[0], e[1], 0, false);
      w = __builtin_amdgcn_cvt_pk_fp8_f32(e[2], e[3], w, true);
      int pr = pgrpL*64 + f*16 + (lane & 15);
      int kl = kgrp*16 + (lane >> 4)*4;
      *(u32*)(ps + pr*64 + (kl ^ ((pr & 7) << 3))) = w;
    }

    __syncthreads();   // P_lds ready; hs free

    // prefetch next hbuf chunk under PV compute
    if (kc + 1 < NCH) {
      #pragma unroll
      for (int r = 0; r < 2; ++r) {
        int f = r*512 + tid;
        int k = f >> 4, u = f & 15;
        gload16(hbg + ((size_t)(kc + 1)*64 + k)*HP + ((u ^ (k & 7))*8), hs + r*4096 + wave*512);
      }
    }

    // PV: acc[p][c] += P * allT
    #pragma unroll
    for (int sl = 0; sl < 2; ++sl) {
      long pa[4];
      #pragma unroll
      for (int mf = 0; mf < 4; ++mf) {
        int pr = pgrpV*64 + mf*16 + (lane & 15);
        int kl = sl*32 + (lane >> 4)*8;
        pa[mf] = *(const long*)(ps + pr*64 + (kl ^ ((pr & 7) << 3)));
      }
      #pragma unroll
      for (int nf = 0; nf < 8; ++nf)
        #pragma unroll
        for (int mf = 0; mf < 4; ++mf)
          acc[mf][nf] = __builtin_amdgcn_mfma_f32_16x16x32_fp8_fp8(pa[mf], breg[nf][sl], acc[mf][nf], 0, 0, 0);
    }
  }

  // reduce exp-sums (block-local)
  #pragma unroll
  for (int f = 0; f < 4; ++f) {
    float s = s_acc[f];
    s += __shfl_xor(s, 16);
    s += __shfl_xor(s, 32);
    if (lane < 16) atomicAdd(&sums[pgrpL*64 + f*16 + lane], s);
  }
  __syncthreads();

  // normalize + store
  #pragma unroll
  for (int mf = 0; mf < 4; ++mf)
    #pragma unroll
    for (int q = 0; q < 4; ++q) {
      int p = pgrpV*64 + mf*16 + (lane >> 4)*4 + q;
      int gp = p0 + p;
      if (gp < PPQ) {
        float inv = 1.0f / sums[p];
        #pragma unroll
        for (int nf = 0; nf < 8; ++nf) {
          int c = cgrp*128 + nf*16 + (lane & 15);
          out[(size_t)b*PPQ*CC + (size_t)gp*CC + c] = acc[mf][nf][q]*inv;
        }
      }
    }
}

extern "C" void kernel_launch(void* const* d_in, const int* in_sizes, int n_in,
                              void* d_out, int out_size, void* d_ws, size_t ws_size,
                              hipStream_t stream)
{
  const float* tokens = (const float*)d_in[0];
  const float* ax  = (const float*)d_in[1];
  const float* ay  = (const float*)d_in[2];
  const float* ln_g = (const float*)d_in[3];
  const float* ln_b = (const float*)d_in[4];
  const float* w1  = (const float*)d_in[5];
  const float* b1  = (const float*)d_in[6];
  const float* w2  = (const float*)d_in[7];
  const float* b2  = (const float*)d_in[8];
  const float* scale = (const float*)d_in[9];
  float* out_super = (float*)d_out;
  float* out_mask  = out_super + (size_t)NB*PPQ*CC;

  char* ws = (char*)d_ws;
  size_t off = 0;
  u64* keys = (u64*)(ws + off);           off += (size_t)NB*LL*8;
  float2* stats = (float2*)(ws + off);    off += 512;
  float* partials = (float*)(ws + off);   off += (size_t)NB*8*CC*4;
  float2* rowstats = (float2*)(ws + off); off += (size_t)NB*KP*8;
  u16* allT = (u16*)(ws + off);           off += (size_t)NB*KP*CC*2;
  u8*  allTT = (u8*)(ws + off);           off += (size_t)NB*CC*KP;
  u16* hbuf  = (u16*)(ws + off);          off += (size_t)NB*KP*HP*2;
  u16* w1T   = (u16*)(ws + off);          off += (size_t)HP*CC*2;
  u16* w2T   = (u16*)(ws + off);          off += (size_t)PPAD*HP*2;
  if (off > ws_size) return;

  prep_kernel<<<704, 256, 0, stream>>>(w1, w2, w1T, w2T);
  sort_kernel<<<NB, 1024, 0, stream>>>(ax, ay, keys, out_mask, stats);
  tail_partial_kernel<<<dim3(8, NB), 256, 0, stream>>>(tokens, keys, stats, partials);
  gather_ln_kernel<<<dim3(KP/4, NB), 256, 0, stream>>>(tokens, keys, partials, allT, rowstats);
  transpose_kernel<<<dim3(KP/64, CC/64, NB), 256, 0, stream>>>(allT, allTT);
  gemm0_kernel<<<(NB*KP)/128, 256, 0, stream>>>(
      allT, w1T, hbuf, b1, rowstats, ln_g, ln_b);
  fused_kernel<<<NB*7, 512, 0, stream>>>(
      hbuf, w2T, allTT, b2, scale, out_super);
}